// Round 1
// baseline (445.635 us; speedup 1.0000x reference)
//
#include <hip/hip_runtime.h>

#define E_EDGES 320000
#define NN 20000
#define HID 128

typedef __attribute__((ext_vector_type(8))) short short8;
typedef __attribute__((ext_vector_type(4))) float f32x4;
typedef __attribute__((ext_vector_type(4))) unsigned short us4;

__device__ __forceinline__ unsigned short f2b(float f) {
  unsigned u = __builtin_bit_cast(unsigned, f);
  u += 0x7fffu + ((u >> 16) & 1u);
  return (unsigned short)(u >> 16);
}

// ---------------- weight prepack: f32 [K][128] -> bf16 MFMA-fragment order ---
// frag layout: dst[((kt*8 + ntg)*64 + lane)*8 + r] = W[kt*32 + (lane>>4)*8 + r][ntg*16 + (lane&15)]
__global__ void prepack_k(const float* __restrict__ Wce1, const float* __restrict__ Wce2,
                          const float* __restrict__ Ws1,  const float* __restrict__ Ws2,
                          const float* __restrict__ Wpe2, const float* __restrict__ Wpe1,
                          unsigned short* __restrict__ dst) {
  int i = blockIdx.x * 256 + threadIdx.x;          // grid covers exactly 102400
  const float* W; int Ksrc, base;
  if (i < 32768)      { W = Wce1; Ksrc = 256; base = 0; }
  else if (i < 49152) { W = Wce2; Ksrc = 128; base = 32768; }
  else if (i < 65536) { W = Ws1;  Ksrc = 128; base = 49152; }
  else if (i < 81920) { W = Ws2;  Ksrc = 128; base = 65536; }
  else if (i < 98304) { W = Wpe2; Ksrc = 128; base = 81920; }
  else                { W = Wpe1; Ksrc = 18;  base = 98304; }
  int j = i - base;
  int r = j & 7, lane = (j >> 3) & 63, ntg = (j >> 9) & 7, kt = j >> 12;
  int sk = kt * 32 + ((lane >> 4) << 3) + r;
  int sn = (ntg << 4) + (lane & 15);
  float v = (sk < Ksrc) ? W[sk * HID + sn] : 0.0f;
  dst[i] = f2b(v);
}

// ---------------- per-edge geometry + segment-sum atomics ---------------------
__global__ void edge_geom_k(const int* __restrict__ erow, const int* __restrict__ ecol,
                            const float* __restrict__ coord,
                            float* __restrict__ nf, float* __restrict__ cnt,
                            float* __restrict__ cdn) {
  int i = blockIdx.x * 256 + threadIdx.x;
  if (i >= E_EDGES) return;
  int r = erow[i], c = ecol[i];
  float dx = coord[r*3+0] - coord[c*3+0];
  float dy = coord[r*3+1] - coord[c*3+1];
  float dz = coord[r*3+2] - coord[c*3+2];
  float r2 = dx*dx + dy*dy + dz*dz;
  float dn = sqrtf(r2);
  float invn = 1.0f / (dn + 1e-8f);
  cdn[i*3+0] = dx*invn; cdn[i*3+1] = dy*invn; cdn[i*3+2] = dz*invn;
  float inv = 1.0f / dn;
  float w3 = inv*inv*inv, w4 = w3*inv, w5 = w4*inv;
  float* p = nf + r*9;
  atomicAdd(p+0, w3*dx); atomicAdd(p+1, w3*dy); atomicAdd(p+2, w3*dz);
  atomicAdd(p+3, w4*dx); atomicAdd(p+4, w4*dy); atomicAdd(p+5, w4*dz);
  atomicAdd(p+6, w5*dx); atomicAdd(p+7, w5*dy); atomicAdd(p+8, w5*dz);
  atomicAdd(cnt + r, 1.0f);
}

// ---------------- per-node normalize -----------------------------------------
__global__ void node_norm_k(const float* __restrict__ nf, const float* __restrict__ cnt,
                            float* __restrict__ nvecs) {
  int n = blockIdx.x * 256 + threadIdx.x;
  if (n >= NN) return;
  float cinv = 1.0f / fmaxf(cnt[n], 1.0f);
  #pragma unroll
  for (int a = 0; a < 3; a++) {
    float x = nf[n*9+a*3+0]*cinv, y = nf[n*9+a*3+1]*cinv, z = nf[n*9+a*3+2]*cinv;
    float nm = sqrtf(x*x + y*y + z*z);
    float s = 1.0f / (nm + 1e-8f);
    nvecs[n*9+a*3+0] = x*s; nvecs[n*9+a*3+1] = y*s; nvecs[n*9+a*3+2] = z*s;
  }
}

// ---------------- fused edge MLP ----------------------------------------------
#define AS 264   // chem_in tile stride (bf16 elems): 528B == 16 mod 128 -> conflict-free b128 reads
#define TS 136   // intermediate stride: 272B == 16 mod 128
#define PS 40    // pos_in stride

template <int NKT>
__device__ __forceinline__ void gemm_frag(const unsigned short* __restrict__ aB, int sAstride,
                                          const unsigned short* __restrict__ wpL,
                                          const float* __restrict__ bias,
                                          int lane, int cl, int kg, int wv, f32x4 (&acc)[4][2]) {
  float bb0 = bias[wv*32 + cl];
  float bb1 = bias[wv*32 + 16 + cl];
  #pragma unroll
  for (int rt = 0; rt < 4; rt++) {
    acc[rt][0] = f32x4{bb0, bb0, bb0, bb0};
    acc[rt][1] = f32x4{bb1, bb1, bb1, bb1};
  }
  #pragma unroll
  for (int kt = 0; kt < NKT; kt++) {
    short8 bf0 = *reinterpret_cast<const short8*>(wpL + ((kt*8 + wv*2 + 0)*64 + lane)*8);
    short8 bf1 = *reinterpret_cast<const short8*>(wpL + ((kt*8 + wv*2 + 1)*64 + lane)*8);
    #pragma unroll
    for (int rt = 0; rt < 4; rt++) {
      short8 af = *reinterpret_cast<const short8*>(aB + (rt*16 + cl)*sAstride + kt*32 + kg*8);
      acc[rt][0] = __builtin_amdgcn_mfma_f32_16x16x32_bf16(af, bf0, acc[rt][0], 0, 0, 0);
      acc[rt][1] = __builtin_amdgcn_mfma_f32_16x16x32_bf16(af, bf1, acc[rt][1], 0, 0, 0);
    }
  }
}

__device__ __forceinline__ void store_silu(f32x4 (&acc)[4][2], unsigned short* dB, int sD,
                                           int cl, int kg, int wv) {
  #pragma unroll
  for (int rt = 0; rt < 4; rt++)
    #pragma unroll
    for (int nt = 0; nt < 2; nt++)
      #pragma unroll
      for (int g = 0; g < 4; g++) {
        int row = rt*16 + kg*4 + g;
        int col = wv*32 + nt*16 + cl;
        float x = acc[rt][nt][g];
        x = x / (1.0f + __expf(-x));          // SiLU
        dB[row*sD + col] = f2b(x);
      }
}

__launch_bounds__(256, 2)
__global__ void fused_k(const int* __restrict__ erow, const int* __restrict__ ecol,
                        const float* __restrict__ h, const float* __restrict__ coord,
                        const float* __restrict__ nvecs,
                        const unsigned short* __restrict__ wp,
                        const float* __restrict__ b1,  const float* __restrict__ b2,
                        const float* __restrict__ bs1, const float* __restrict__ bs2,
                        const float* __restrict__ bp1, const float* __restrict__ bp2,
                        const float* __restrict__ watt, const float* __restrict__ batt,
                        float* __restrict__ out0, float* __restrict__ chem_o,
                        float* __restrict__ pos_o) {
  __shared__ unsigned short sA[64 * AS];   // chem_in [64][256] ; later reused (stride TS) for pe1 out
  __shared__ unsigned short sT[64 * TS];   // t1 / s1
  __shared__ unsigned short sC[64 * TS];   // chem bf16
  __shared__ unsigned short sPin[64 * PS]; // pos_in [64][32] (18 real + zero pad)
  __shared__ int sEr[64], sEc[64];
  __shared__ float sAtt[64];

  const int tid = threadIdx.x;
  const int lane = tid & 63;
  const int wv = tid >> 6;
  const int cl = lane & 15;
  const int kg = lane >> 4;
  const int e0 = blockIdx.x * 64;

  if (tid < 64) {
    sEr[tid] = erow[e0 + tid];
    sEc[tid] = ecol[e0 + tid];
    sAtt[tid] = 0.0f;
  }
  __syncthreads();

  // ---- phase 1: per-edge geometry -> pos_in (threads 0..63) ----
  if (tid < 64) {
    int r = sEr[tid], c = sEc[tid];
    float dx = coord[r*3+0] - coord[c*3+0];
    float dy = coord[r*3+1] - coord[c*3+1];
    float dz = coord[r*3+2] - coord[c*3+2];
    float r2 = dx*dx + dy*dy + dz*dz;
    #pragma unroll
    for (int a = 0; a < 3; a++) {
      float s = nvecs[r*9+a*3+0]*nvecs[c*9+a*3+0]
              + nvecs[r*9+a*3+1]*nvecs[c*9+a*3+1]
              + nvecs[r*9+a*3+2]*nvecs[c*9+a*3+2];
      sPin[tid*PS + a] = f2b(s);
    }
    float t = 1.0f;
    #pragma unroll
    for (int s = 0; s < 15; s++) {
      sPin[tid*PS + 3 + s] = f2b(__expf(r2 * (-0.5f / t)));
      t *= 2.25f;
    }
    #pragma unroll
    for (int k = 18; k < 32; k++) sPin[tid*PS + k] = 0;
  }

  // ---- gather chem_in = [h[row] | h[col]] -> sA (bf16) ----
  #pragma unroll
  for (int it = 0; it < 16; ++it) {
    int f = it * 256 + tid;
    int e = f >> 6, c4 = f & 63;
    int node = (c4 < 32) ? sEr[e] : sEc[e];
    int cc = (c4 & 31) << 2;
    const float4 v = *reinterpret_cast<const float4*>(h + node * HID + cc);
    us4 b; b.x = f2b(v.x); b.y = f2b(v.y); b.z = f2b(v.z); b.w = f2b(v.w);
    *reinterpret_cast<us4*>(&sA[e * AS + c4 * 4]) = b;   // dcol == c4*4
  }
  __syncthreads();

  f32x4 acc[4][2];

  // ---- ce1: [64,256] x [256,128] + b, SiLU -> sT ----
  gemm_frag<8>(sA, AS, wp + 0, b1, lane, cl, kg, wv, acc);
  store_silu(acc, sT, TS, cl, kg, wv);
  __syncthreads();

  // ---- ce2: -> chem (f32 out) + sC (bf16) ----
  gemm_frag<4>(sT, TS, wp + 32768, b2, lane, cl, kg, wv, acc);
  #pragma unroll
  for (int rt = 0; rt < 4; rt++)
    #pragma unroll
    for (int nt = 0; nt < 2; nt++)
      #pragma unroll
      for (int g = 0; g < 4; g++) {
        int row = rt*16 + kg*4 + g;
        int col = wv*32 + nt*16 + cl;
        float x = acc[rt][nt][g];
        chem_o[(size_t)(e0 + row) * HID + col] = x;
        sC[row*TS + col] = f2b(x);
      }
  __syncthreads();

  // ---- s1: SiLU -> sT ----
  gemm_frag<4>(sC, TS, wp + 49152, bs1, lane, cl, kg, wv, acc);
  store_silu(acc, sT, TS, cl, kg, wv);
  __syncthreads();

  // ---- s2: keep in regs ----
  f32x4 accS[4][2];
  gemm_frag<4>(sT, TS, wp + 65536, bs2, lane, cl, kg, wv, accS);

  // ---- pe1 (K=32 padded): SiLU -> sA (stride TS) ----
  gemm_frag<1>(sPin, PS, wp + 98304, bp1, lane, cl, kg, wv, acc);
  store_silu(acc, sA, TS, cl, kg, wv);
  __syncthreads();

  // ---- pe2: pos out; o = s2 * pos ----
  gemm_frag<4>(sA, TS, wp + 81920, bp2, lane, cl, kg, wv, acc);
  #pragma unroll
  for (int rt = 0; rt < 4; rt++)
    #pragma unroll
    for (int nt = 0; nt < 2; nt++)
      #pragma unroll
      for (int g = 0; g < 4; g++) {
        int row = rt*16 + kg*4 + g;
        int col = wv*32 + nt*16 + cl;
        float p = acc[rt][nt][g];
        pos_o[(size_t)(e0 + row) * HID + col] = p;
        accS[rt][nt][g] *= p;                 // accS now holds o
      }

  // ---- attention: att = sigmoid(o . w_att + b_att) per row ----
  float wa0 = watt[wv*32 + cl];
  float wa1 = watt[wv*32 + 16 + cl];
  #pragma unroll
  for (int rt = 0; rt < 4; rt++)
    #pragma unroll
    for (int g = 0; g < 4; g++) {
      float part = accS[rt][0][g]*wa0 + accS[rt][1][g]*wa1;
      part += __shfl_xor(part, 1);
      part += __shfl_xor(part, 2);
      part += __shfl_xor(part, 4);
      part += __shfl_xor(part, 8);
      if (cl == 0) atomicAdd(&sAtt[rt*16 + kg*4 + g], part);
    }
  __syncthreads();

  float ba = batt[0];
  #pragma unroll
  for (int rt = 0; rt < 4; rt++)
    #pragma unroll
    for (int g = 0; g < 4; g++) {
      int row = rt*16 + kg*4 + g;
      float av = 1.0f / (1.0f + __expf(-(sAtt[row] + ba)));
      #pragma unroll
      for (int nt = 0; nt < 2; nt++) {
        int col = wv*32 + nt*16 + cl;
        out0[(size_t)(e0 + row) * HID + col] = accS[rt][nt][g] * av;
      }
    }
}

// ---------------- launcher ----------------------------------------------------
extern "C" void kernel_launch(void* const* d_in, const int* in_sizes, int n_in,
                              void* d_out, int out_size, void* d_ws, size_t ws_size,
                              hipStream_t stream) {
  (void)in_sizes; (void)n_in; (void)out_size; (void)ws_size;
  const float* h     = (const float*)d_in[0];
  const float* coord = (const float*)d_in[1];
  const int*   edges = (const int*)d_in[2];
  const float* W_ce1 = (const float*)d_in[3];  const float* b_ce1 = (const float*)d_in[4];
  const float* W_ce2 = (const float*)d_in[5];  const float* b_ce2 = (const float*)d_in[6];
  const float* W_pe1 = (const float*)d_in[7];  const float* b_pe1 = (const float*)d_in[8];
  const float* W_pe2 = (const float*)d_in[9];  const float* b_pe2 = (const float*)d_in[10];
  const float* W_s1  = (const float*)d_in[11]; const float* b_s1  = (const float*)d_in[12];
  const float* W_s2  = (const float*)d_in[13]; const float* b_s2  = (const float*)d_in[14];
  const float* W_att = (const float*)d_in[15]; const float* b_att = (const float*)d_in[16];

  float* out  = (float*)d_out;
  float* chem = out  + (size_t)E_EDGES * HID;
  float* pos  = chem + (size_t)E_EDGES * HID;
  float* cdn  = pos  + (size_t)E_EDGES * HID;

  float* nf    = (float*)d_ws;              // [NN*9]
  float* cnt   = nf + NN * 9;               // [NN]
  float* nvecs = cnt + NN;                  // [NN*9]
  unsigned short* wpack = (unsigned short*)(nvecs + NN * 9);  // 102400 bf16 (16B-aligned)

  hipMemsetAsync(nf, 0, (size_t)(NN * 10) * sizeof(float), stream);
  prepack_k<<<400, 256, 0, stream>>>(W_ce1, W_ce2, W_s1, W_s2, W_pe2, W_pe1, wpack);
  edge_geom_k<<<(E_EDGES + 255) / 256, 256, 0, stream>>>(edges, edges + E_EDGES, coord,
                                                         nf, cnt, cdn);
  node_norm_k<<<(NN + 255) / 256, 256, 0, stream>>>(nf, cnt, nvecs);
  fused_k<<<E_EDGES / 64, 256, 0, stream>>>(edges, edges + E_EDGES, h, coord, nvecs, wpack,
                                            b_ce1, b_ce2, b_s1, b_s2, b_pe1, b_pe2,
                                            W_att, b_att, out, chem, pos);
}